// Round 3
// baseline (361.192 us; speedup 1.0000x reference)
//
#include <hip/hip_runtime.h>
#include <math.h>

#define Bb 4
#define Ss 512
#define Hh 768
#define Vv 30522
#define Aa 200

typedef float f32x4 __attribute__((ext_vector_type(4)));
typedef short short8 __attribute__((ext_vector_type(8)));
typedef short short4v __attribute__((ext_vector_type(4)));
typedef __bf16 bf16x8 __attribute__((ext_vector_type(8)));

__device__ __forceinline__ unsigned short f2bf(float f) {
  union { float f; unsigned u; } v; v.f = f;
  unsigned r = v.u + 0x7FFFu + ((v.u >> 16) & 1u);
  return (unsigned short)(r >> 16);
}

__device__ __forceinline__ void gload16(const void* g, void* l) {
  __builtin_amdgcn_global_load_lds(
      (const __attribute__((address_space(1))) void*)g,
      (__attribute__((address_space(3))) void*)l, 16, 0, 0);
}

#define BAR()   do { asm volatile("" ::: "memory"); __builtin_amdgcn_s_barrier(); asm volatile("" ::: "memory"); } while(0)
#define LGKM0() do { asm volatile("s_waitcnt lgkmcnt(0)" ::: "memory"); __builtin_amdgcn_sched_barrier(0); } while(0)
#define VMW(n)  asm volatile("s_waitcnt vmcnt(" #n ")" ::: "memory")

// ---------------- K0: fp32 -> bf16 weight conversion -----------------------
__global__ __launch_bounds__(256) void wconv(
    const float* __restrict__ src, unsigned short* __restrict__ dst, int n4)
{
  int i = blockIdx.x * 256 + threadIdx.x;
  const int stride = gridDim.x * 256;
  for (; i < n4; i += stride) {
    f32x4 v = *reinterpret_cast<const f32x4*>(src + (size_t)i * 4);
    short4v p;
    #pragma unroll
    for (int q = 0; q < 4; ++q) p[q] = (short)f2bf(v[q]);
    *reinterpret_cast<short4v*>(dst + (size_t)i * 4) = p;
  }
}

// ---------------- K1: s[tok] = sum_a v_a * tanh(W1[a,:].h[tok] + b1[a]) ----
#define K1_TOK 8
__global__ __launch_bounds__(256) void k1_score(
    const float* __restrict__ hidden, const float* __restrict__ W1,
    const float* __restrict__ b1, const float* __restrict__ v_attn,
    float* __restrict__ s_buf)
{
  __shared__ float hsm[K1_TOK][Hh];
  __shared__ float part[K1_TOK][4];
  const int tid = threadIdx.x;
  const int tok0 = blockIdx.x * K1_TOK;
  #pragma unroll
  for (int i = 0; i < (K1_TOK * Hh / 4) / 256; ++i) {
    int c = i * 256 + tid;
    int row = c / (Hh / 4);
    int col4 = c % (Hh / 4);
    f32x4 v = *reinterpret_cast<const f32x4*>(hidden + (size_t)(tok0 + row) * Hh + col4 * 4);
    *reinterpret_cast<f32x4*>(&hsm[row][col4 * 4]) = v;
  }
  __syncthreads();
  float acc[K1_TOK];
  #pragma unroll
  for (int t = 0; t < K1_TOK; ++t) acc[t] = 0.f;
  if (tid < Aa) {
    const float* wr = W1 + (size_t)tid * Hh;
    for (int h = 0; h < Hh; h += 4) {
      f32x4 w4 = *reinterpret_cast<const f32x4*>(wr + h);
      #pragma unroll
      for (int t = 0; t < K1_TOK; ++t) {
        f32x4 h4 = *reinterpret_cast<const f32x4*>(&hsm[t][h]);
        acc[t] += w4[0]*h4[0] + w4[1]*h4[1] + w4[2]*h4[2] + w4[3]*h4[3];
      }
    }
  }
  const int lane = tid & 63, wv = tid >> 6;
  #pragma unroll
  for (int t = 0; t < K1_TOK; ++t) {
    float x = (tid < Aa) ? v_attn[tid] * tanhf(acc[t] + b1[tid]) : 0.f;
    #pragma unroll
    for (int o = 32; o > 0; o >>= 1) x += __shfl_xor(x, o);
    if (lane == 0) part[t][wv] = x;
  }
  __syncthreads();
  if (tid < K1_TOK)
    s_buf[tok0 + tid] = part[tid][0] + part[tid][1] + part[tid][2] + part[tid][3];
}

// ---------------- K1.5: per-batch e = exp(s-max), prefix + suffix sums -----
#define ZLD 520
__global__ __launch_bounds__(256) void k15_pre(
    const float* __restrict__ s_buf, float* __restrict__ e_buf,
    float* __restrict__ zpref, float* __restrict__ zsuf)
{
  const int b = blockIdx.x, tid = threadIdx.x;
  __shared__ float se[512];
  __shared__ float bA[512], bB[512];
  __shared__ float pm[4];
  float v0 = s_buf[b * 512 + tid], v1 = s_buf[b * 512 + 256 + tid];
  float m = fmaxf(v0, v1);
  #pragma unroll
  for (int o = 32; o > 0; o >>= 1) m = fmaxf(m, __shfl_xor(m, o));
  if ((tid & 63) == 0) pm[tid >> 6] = m;
  __syncthreads();
  float M = fmaxf(fmaxf(pm[0], pm[1]), fmaxf(pm[2], pm[3]));
  float e0 = expf(v0 - M), e1 = expf(v1 - M);
  se[tid] = e0; se[tid + 256] = e1;
  e_buf[b * 512 + tid] = e0; e_buf[b * 512 + 256 + tid] = e1;
  bA[tid] = e0; bA[tid + 256] = e1;
  __syncthreads();
  float* src = bA; float* dst = bB;
  for (int off = 1; off < 512; off <<= 1) {
    for (int i = tid; i < 512; i += 256)
      dst[i] = src[i] + ((i >= off) ? src[i - off] : 0.f);
    __syncthreads();
    float* t = src; src = dst; dst = t;
  }
  if (tid == 0) zpref[b * ZLD] = 0.f;
  zpref[b * ZLD + 1 + tid] = src[tid];
  zpref[b * ZLD + 257 + tid] = src[tid + 256];
  __syncthreads();
  src[tid] = se[tid]; src[tid + 256] = se[tid + 256];
  __syncthreads();
  for (int off = 1; off < 512; off <<= 1) {
    for (int i = tid; i < 512; i += 256)
      dst[i] = src[i] + ((i + off < 512) ? src[i + off] : 0.f);
    __syncthreads();
    float* t = src; src = dst; dst = t;
  }
  zsuf[b * ZLD + tid] = src[tid];
  zsuf[b * ZLD + 256 + tid] = src[tid + 256];
  if (tid == 0) zsuf[b * ZLD + 512] = 0.f;
}

// ---------------- K2a: per-64-chunk partial sums of e_k * h[k][f] ----------
__global__ __launch_bounds__(256) void k2a_part(
    const float* __restrict__ hidden, const float* __restrict__ e_buf,
    float* __restrict__ spart)
{
  const int bid = blockIdx.x;
  const int fc = bid % 3, c = (bid / 3) % 8, b = bid / 24;
  const int f = fc * 256 + threadIdx.x;
  float acc = 0.f;
  for (int kk = 0; kk < 64; ++kk) {
    int k = c * 64 + kk;
    acc += e_buf[b * 512 + k] * hidden[((size_t)(b * 512 + k)) * Hh + f];
  }
  spart[((size_t)b * 8 + c) * Hh + f] = acc;
}

// ---------------- K2c: scan -> hidd (fp32 to d_out, bf16 to ws) ------------
__global__ __launch_bounds__(256) void k2c_scan(
    const float* __restrict__ hidden, const float* __restrict__ e_buf,
    const float* __restrict__ zpref, const float* __restrict__ zsuf,
    const float* __restrict__ spart, const int* __restrict__ ptype,
    float* __restrict__ out_hidd, unsigned short* __restrict__ hbf)
{
  const int bid = blockIdx.x;
  const int fc = bid % 3, jc = (bid / 3) % 8, b = bid / 24;
  const int f = fc * 256 + threadIdx.x;
  const int type = ptype[b];
  const float* Sp = spart + (size_t)b * 8 * Hh;
  const float* Zp = zpref + b * ZLD;
  const float* Zs = zsuf + b * ZLD;
  const size_t hbase = (size_t)b * 512 * Hh + f;
  if (type == 0) {
    float run = 0.f;
    for (int c = 0; c < jc; ++c) run += Sp[c * Hh + f];
    for (int jj = 0; jj < 64; ++jj) {
      int j = jc * 64 + jj;
      float ev = e_buf[b * 512 + j];
      float h = hidden[hbase + (size_t)j * Hh];
      run += ev * h;
      float val = run / (Zp[j + 1] * (float)(j + 1));
      out_hidd[hbase + (size_t)j * Hh] = val;
      hbf[hbase + (size_t)j * Hh] = f2bf(val);
    }
  } else if (type == 1) {
    float run = 0.f;
    for (int c = jc + 1; c < 8; ++c) run += Sp[c * Hh + f];
    for (int jj = 63; jj >= 0; --jj) {
      int j = jc * 64 + jj;
      float ev = e_buf[b * 512 + j];
      float h = hidden[hbase + (size_t)j * Hh];
      run += ev * h;
      float val = run / (Zs[j] * (float)(512 - j));
      out_hidd[hbase + (size_t)j * Hh] = val;
      hbf[hbase + (size_t)j * Hh] = f2bf(val);
    }
  } else {
    float T = 0.f;
    for (int c = 0; c < 8; ++c) T += Sp[c * Hh + f];
    float Ztot = Zp[512];
    for (int jj = 0; jj < 64; ++jj) {
      int j = jc * 64 + jj;
      float ev = e_buf[b * 512 + j];
      float h = hidden[hbase + (size_t)j * Hh];
      float val = (T - ev * h) / ((Ztot - ev) * 511.0f);
      out_hidd[hbase + (size_t)j * Hh] = val;
      hbf[hbase + (size_t)j * Hh] = f2bf(val);
    }
  }
}

// ---------------- gemm8: 256x256 8-wave 4-phase pipelined bf16 GEMM --------
// C[m,n] = sum_k A[m,k]*B[n,k] + bias[n]; A [M][K] bf16, B [N][K] bf16.
// LDS: 2 buffers x (A 32KB + B 32KB) = 128KB; halves of 128 rows (16KB).
// Swizzle: row r, 16B-chunk c stored at slot c^(r&7) (zero-conflict, r2-proven);
// linear LDS dest for global_load_lds + inverse-swizzled global source.
// Schedule per K-tile t (4 phases, 16 MFMA each):
//  ph0: RD A(m0-3)+B(n0-1); STG B0(t+1)->nxt | bar lgkm0 MFMA Q00 bar
//  ph1: RD B(n2-3);         STG B1(t+1)->nxt | bar lgkm0 MFMA Q01 bar
//  ph2: RD A(m4-7);                          | bar lgkm0 MFMA Q10 bar
//  ph3: STG A0+A1(t+2)->cur (A reads done by ph2 barrier); MFMA Q11;
//       vmcnt(4) [leaves t+2's A in flight]; bar
__global__ __launch_bounds__(512, 2) void gemm8(
    const unsigned short* __restrict__ Abf, const unsigned short* __restrict__ Bbf,
    const float* __restrict__ bias, float* __restrict__ C,
    const int M, const int N, const int K, const int ntm)
{
  __shared__ __attribute__((aligned(16))) unsigned char lds8[131072];
  const int tid = threadIdx.x;
  const int total = gridDim.x;
  int bid = blockIdx.x;
  if ((total & 7) == 0) bid = (bid & 7) * (total >> 3) + (bid >> 3);  // XCD-chunked
  const int bm = bid % ntm;          // bn-major within XCD chunk: B tile L2-hot
  const int bn = bid / ntm;
  const int lane = tid & 63;
  const int wv = tid >> 6;           // 0..7
  const int wr = wv >> 2;            // 0..1 -> rows wr*128
  const int wc = wv & 3;             // 0..3 -> cols wc*64
  const int r15 = lane & 15, kg = lane >> 4;
  const int nt = K / 64;

  // staging geometry
  int ldso[2];
  size_t goffA[2][2], goffB[2][2];   // [h][i]
  #pragma unroll
  for (int i = 0; i < 2; ++i) {
    int q = i * 512 + tid;
    int r = q >> 3, s = q & 7;
    int c = s ^ (r & 7);
    ldso[i] = q * 16;
    #pragma unroll
    for (int h = 0; h < 2; ++h) {
      int ra = bm * 256 + h * 128 + r;
      goffA[h][i] = (size_t)ra * K + c * 8;
      int rb = bn * 256 + h * 128 + r; if (rb >= N) rb = N - 1;
      goffB[h][i] = (size_t)rb * K + c * 8;
    }
  }
  const int slot0 = ((kg) ^ (r15 & 7)) * 16;       // ks=0 chunk
  const int slot1 = ((4 + kg) ^ (r15 & 7)) * 16;   // ks=1 chunk

#define STG_A(t, d) do { \
    unsigned char* lb_ = lds8 + (d) * 65536; \
    gload16(Abf + goffA[0][0] + (size_t)(t) * 64, lb_ + ldso[0]); \
    gload16(Abf + goffA[0][1] + (size_t)(t) * 64, lb_ + ldso[1]); \
    gload16(Abf + goffA[1][0] + (size_t)(t) * 64, lb_ + 16384 + ldso[0]); \
    gload16(Abf + goffA[1][1] + (size_t)(t) * 64, lb_ + 16384 + ldso[1]); \
  } while (0)
#define STG_B(t, h, d) do { \
    unsigned char* lb_ = lds8 + (d) * 65536 + 32768 + (h) * 16384; \
    gload16(Bbf + goffB[h][0] + (size_t)(t) * 64, lb_ + ldso[0]); \
    gload16(Bbf + goffB[h][1] + (size_t)(t) * 64, lb_ + ldso[1]); \
  } while (0)
#define RD_A(mg, d) do { \
    const unsigned char* ab_ = lds8 + (d) * 65536 + wr * 16384 + r15 * 128; \
    _Pragma("unroll") \
    for (int mm = 0; mm < 4; ++mm) { \
      af[mm * 2 + 0] = *reinterpret_cast<const bf16x8*>(ab_ + ((mg) * 4 + mm) * 2048 + slot0); \
      af[mm * 2 + 1] = *reinterpret_cast<const bf16x8*>(ab_ + ((mg) * 4 + mm) * 2048 + slot1); \
    } \
  } while (0)
#define RD_B(ng, d) do { \
    const unsigned char* bb_ = lds8 + (d) * 65536 + 32768 + (wc >> 1) * 16384 + ((wc & 1) * 64 + r15) * 128; \
    _Pragma("unroll") \
    for (int nn = 0; nn < 2; ++nn) { \
      bfr[((ng) * 2 + nn) * 2 + 0] = *reinterpret_cast<const bf16x8*>(bb_ + ((ng) * 2 + nn) * 2048 + slot0); \
      bfr[((ng) * 2 + nn) * 2 + 1] = *reinterpret_cast<const bf16x8*>(bb_ + ((ng) * 2 + nn) * 2048 + slot1); \
    } \
  } while (0)
#define MFMAQ(mg, ng) do { \
    _Pragma("unroll") \
    for (int mm = 0; mm < 4; ++mm) { \
      _Pragma("unroll") \
      for (int nn = 0; nn < 2; ++nn) { \
        const int n_ = (ng) * 2 + nn; \
        acc[(mg) * 4 + mm][n_] = __builtin_amdgcn_mfma_f32_16x16x32_bf16(af[mm * 2 + 0], bfr[n_ * 2 + 0], acc[(mg) * 4 + mm][n_], 0, 0, 0); \
        acc[(mg) * 4 + mm][n_] = __builtin_amdgcn_mfma_f32_16x16x32_bf16(af[mm * 2 + 1], bfr[n_ * 2 + 1], acc[(mg) * 4 + mm][n_], 0, 0, 0); \
      } \
    } \
  } while (0)

  f32x4 acc[8][4];
  #pragma unroll
  for (int m = 0; m < 8; ++m)
    #pragma unroll
    for (int n = 0; n < 4; ++n)
      #pragma unroll
      for (int r = 0; r < 4; ++r) acc[m][n][r] = 0.f;
  bf16x8 af[8], bfr[8];

  // prologue: A(t0), B(t0), A(t1); wait t0 landed (leave t1's A in flight)
  STG_A(0, 0);
  STG_B(0, 0, 0);
  STG_B(0, 1, 0);
  if (nt > 1) { STG_A(1, 1); VMW(4); } else { VMW(0); }
  BAR();

  for (int t = 0; t < nt; ++t) {
    const int cur = t & 1, nxt = cur ^ 1;
    // ph0
    RD_A(0, cur);
    RD_B(0, cur);
    if (t + 1 < nt) STG_B(t + 1, 0, nxt);
    BAR(); LGKM0();
    __builtin_amdgcn_s_setprio(1); MFMAQ(0, 0); __builtin_amdgcn_s_setprio(0);
    BAR();
    // ph1
    RD_B(1, cur);
    if (t + 1 < nt) STG_B(t + 1, 1, nxt);
    BAR(); LGKM0();
    __builtin_amdgcn_s_setprio(1); MFMAQ(0, 1); __builtin_amdgcn_s_setprio(0);
    BAR();
    // ph2
    RD_A(1, cur);
    BAR(); LGKM0();
    __builtin_amdgcn_s_setprio(1); MFMAQ(1, 0); __builtin_amdgcn_s_setprio(0);
    BAR();
    // ph3
    if (t + 2 < nt) STG_A(t + 2, cur);
    __builtin_amdgcn_s_setprio(1); MFMAQ(1, 1); __builtin_amdgcn_s_setprio(0);
    if (t + 2 < nt) { VMW(4); } else { VMW(0); }
    BAR();
  }

  // epilogue
  #pragma unroll
  for (int n = 0; n < 4; ++n) {
    int col = bn * 256 + wc * 64 + n * 16 + r15;
    if (col < N) {
      float bv = bias[col];
      #pragma unroll
      for (int m = 0; m < 8; ++m) {
        int rb = bm * 256 + wr * 128 + m * 16 + kg * 4;
        #pragma unroll
        for (int rr = 0; rr < 4; ++rr)
          C[(size_t)(rb + rr) * N + col] = acc[m][n][rr] + bv;
      }
    }
  }
#undef STG_A
#undef STG_B
#undef RD_A
#undef RD_B
#undef MFMAQ
}

// ---------------- gemm_bb (128x128, r2-proven): used for FC ----------------
#define GBM 128
#define GBN 128
#define GBK 64
__global__ __launch_bounds__(256) void gemm_bb(
    const unsigned short* __restrict__ Abf, const unsigned short* __restrict__ Bbf,
    const float* __restrict__ bias, float* __restrict__ C,
    const int M, const int N, const int K, const int ntm)
{
  __shared__ unsigned short As[GBM * GBK];
  __shared__ unsigned short Bs[GBN * GBK];
  const int tid = threadIdx.x;
  const int total = gridDim.x;
  int bid = blockIdx.x;
  if ((total & 7) == 0) bid = (bid & 7) * (total >> 3) + (bid >> 3);
  const int bm = bid % ntm;
  const int bn = bid / ntm;
  const int lane = tid & 63;
  const int wv = tid >> 6;
  const int wr = wv >> 1, wc = wv & 1;
  const int r15 = lane & 15, kg = lane >> 4;

  const unsigned short* ga[4];
  const unsigned short* gb[4];
  unsigned short* la[4];
  unsigned short* lb[4];
  #pragma unroll
  for (int i = 0; i < 4; ++i) {
    int qq = i * 256 + tid;
    int r = qq >> 3;
    int ks = (qq & 7) ^ (r & 7);
    ga[i] = Abf + (size_t)(bm * GBM + r) * K + ks * 8;
    int rowb = bn * GBN + r; rowb = rowb < N ? rowb : N - 1;
    gb[i] = Bbf + (size_t)rowb * K + ks * 8;
    la[i] = &As[qq * 8];
    lb[i] = &Bs[qq * 8];
  }

  f32x4 acc[4][4];
  #pragma unroll
  for (int m = 0; m < 4; ++m)
    #pragma unroll
    for (int n = 0; n < 4; ++n)
      #pragma unroll
      for (int r = 0; r < 4; ++r) acc[m][n][r] = 0.f;

  for (int kt = 0; kt < K; kt += GBK) {
    __syncthreads();
    #pragma unroll
    for (int i = 0; i < 4; ++i) gload16(ga[i] + kt, la[i]);
    #pragma unroll
    for (int i = 0; i < 4; ++i) gload16(gb[i] + kt, lb[i]);
    __syncthreads();
    #pragma unroll
    for (int kk = 0; kk < GBK / 32; ++kk) {
      bf16x8 af[4], bf[4];
      #pragma unroll
      for (int m = 0; m < 4; ++m) {
        int ra = wr * 64 + m * 16 + r15;
        int ck = ((kk << 2) | kg) ^ (ra & 7);
        af[m] = *reinterpret_cast<const bf16x8*>(&As[ra * GBK + ck * 8]);
      }
      #pragma unroll
      for (int n = 0; n < 4; ++n) {
        int rb = wc * 64 + n * 16 + r15;
        int ck = ((kk << 2) | kg) ^ (rb & 7);
        bf[n] = *reinterpret_cast<const bf16x8*>(&Bs[rb * GBK + ck * 8]);
      }
      #pragma unroll
      for (int m = 0; m < 4; ++m)
        #pragma unroll
        for (int n = 0; n < 4; ++n)
          acc[m][n] = __builtin_amdgcn_mfma_f32_16x16x32_bf16(af[m], bf[n], acc[m][n], 0, 0, 0);
    }
  }
  #pragma unroll
  for (int n = 0; n < 4; ++n) {
    int col = bn * GBN + wc * 64 + n * 16 + r15;
    if (col < N) {
      float bv = bias[col];
      #pragma unroll
      for (int m = 0; m < 4; ++m) {
        int rbase = bm * GBM + wr * 64 + m * 16 + kg * 4;
        #pragma unroll
        for (int r = 0; r < 4; ++r)
          C[(size_t)(rbase + r) * N + col] = acc[m][n][r] + bv;
      }
    }
  }
}

// ---------------- fallback GEMM (fp32 B, on-the-fly convert) ---------------
__global__ __launch_bounds__(256) void gemm_bt(
    const unsigned short* __restrict__ Abf, const float* __restrict__ Bsrc,
    const float* __restrict__ bias, float* __restrict__ C,
    const int M, const int N, const int K, const int ntm)
{
  __shared__ unsigned short As[GBM * GBK];
  __shared__ unsigned short Bs[GBN * GBK];
  const int tid = threadIdx.x;
  const int total = gridDim.x;
  int bid = blockIdx.x;
  if ((total & 7) == 0) bid = (bid & 7) * (total >> 3) + (bid >> 3);
  const int bm = bid % ntm;
  const int bn = bid / ntm;
  const int lane = tid & 63;
  const int wv = tid >> 6;
  const int wr = wv >> 1, wc = wv & 1;
  const int r15 = lane & 15, kg = lane >> 4;

  f32x4 acc[4][4];
  #pragma unroll
  for (int m = 0; m < 4; ++m)
    #pragma unroll
    for (int n = 0; n < 4; ++n)
      #pragma unroll
      for (int r = 0; r < 4; ++r) acc[m][n][r] = 0.f;

  for (int kt = 0; kt < K; kt += GBK) {
    __syncthreads();
    #pragma unroll
    for (int i = 0; i < 4; ++i) {
      int c = i * 256 + tid;
      int row = c >> 3, col8 = c & 7;
      short8 v = *reinterpret_cast<const short8*>(Abf + (size_t)(bm * GBM + row) * K + kt + col8 * 8);
      int idx = (row * GBK + col8 * 8) ^ ((row & 7) << 3);
      *reinterpret_cast<short8*>(&As[idx]) = v;
    }
    #pragma unroll
    for (int i = 0; i < 8; ++i) {
      int c = i * 256 + tid;
      int row = c >> 4, col4 = c & 15;
      int nsrc = bn * GBN + row; nsrc = nsrc < N ? nsrc : N - 1;
      f32x4 v = *reinterpret_cast<const f32x4*>(Bsrc + (size_t)nsrc * K + kt + col4 * 4);
      short4v p;
      #pragma unroll
      for (int q = 0; q < 4; ++q) p[q] = (short)f2bf(v[q]);
      int idx = (row * GBK + col4 * 4) ^ ((row & 7) << 3);
      *reinterpret_cast<short4v*>(&Bs[idx]) = p;
    }
    __syncthreads();
    #pragma unroll
    for (int kk = 0; kk < GBK / 32; ++kk) {
      bf16x8 af[4], bf[4];
      #pragma unroll
      for (int m = 0; m < 4; ++m) {
        int row = wr * 64 + m * 16 + r15;
        int col = kk * 32 + kg * 8;
        af[m] = *reinterpret_cast<const bf16x8*>(&As[(row * GBK + col) ^ ((row & 7) << 3)]);
      }
      #pragma unroll
      for (int n = 0; n < 4; ++n) {
        int row = wc * 64 + n * 16 + r15;
        int col = kk * 32 + kg * 8;
        bf[n] = *reinterpret_cast<const bf16x8*>(&Bs[(row * GBK + col) ^ ((row & 7) << 3)]);
      }
      #pragma unroll
      for (int m = 0; m < 4; ++m)
        #pragma unroll
        for (int n = 0; n < 4; ++n)
          acc[m][n] = __builtin_amdgcn_mfma_f32_16x16x32_bf16(af[m], bf[n], acc[m][n], 0, 0, 0);
    }
  }
  #pragma unroll
  for (int n = 0; n < 4; ++n) {
    int col = bn * GBN + wc * 64 + n * 16 + r15;
    if (col < N) {
      float bv = bias[col];
      #pragma unroll
      for (int m = 0; m < 4; ++m) {
        int rbase = bm * GBM + wr * 64 + m * 16 + kg * 4;
        #pragma unroll
        for (int r = 0; r < 4; ++r)
          C[(size_t)(rbase + r) * N + col] = acc[m][n][r] + bv;
      }
    }
  }
}

// ---------------- K3b: exact GELU + LayerNorm -> xn (bf16) -----------------
__global__ __launch_bounds__(256) void k3b_geluln(
    const float* __restrict__ x, const float* __restrict__ gam,
    const float* __restrict__ bet, unsigned short* __restrict__ xnbf)
{
  const int row = blockIdx.x, tid = threadIdx.x;
  __shared__ float part[4];
  float g[3];
  float s = 0.f;
  #pragma unroll
  for (int i = 0; i < 3; ++i) {
    float xv = x[(size_t)row * Hh + tid + 256 * i];
    float t = 0.5f * xv * (1.f + erff(xv * 0.70710678118654752f));
    g[i] = t; s += t;
  }
  #pragma unroll
  for (int o = 32; o > 0; o >>= 1) s += __shfl_xor(s, o);
  if ((tid & 63) == 0) part[tid >> 6] = s;
  __syncthreads();
  float mu = (part[0] + part[1] + part[2] + part[3]) * (1.f / 768.f);
  __syncthreads();
  float vs = 0.f;
  #pragma unroll
  for (int i = 0; i < 3; ++i) { float d = g[i] - mu; vs += d * d; }
  #pragma unroll
  for (int o = 32; o > 0; o >>= 1) vs += __shfl_xor(vs, o);
  if ((tid & 63) == 0) part[tid >> 6] = vs;
  __syncthreads();
  float var = (part[0] + part[1] + part[2] + part[3]) * (1.f / 768.f);
  float inv = 1.0f / sqrtf(var + 1e-12f);
  #pragma unroll
  for (int i = 0; i < 3; ++i) {
    int f = tid + 256 * i;
    xnbf[(size_t)row * Hh + f] = f2bf((g[i] - mu) * inv * gam[f] + bet[f]);
  }
}

extern "C" void kernel_launch(void* const* d_in, const int* in_sizes, int n_in,
                              void* d_out, int out_size, void* d_ws, size_t ws_size,
                              hipStream_t stream)
{
  const float* hidden = (const float*)d_in[0];
  const int*   ptype  = (const int*)d_in[1];
  const float* W1     = (const float*)d_in[2];
  const float* b1     = (const float*)d_in[3];
  const float* vat    = (const float*)d_in[4];
  const float* Wfc    = (const float*)d_in[5];
  const float* bfc    = (const float*)d_in[6];
  const float* lng    = (const float*)d_in[7];
  const float* lnb    = (const float*)d_in[8];
  const float* Wout   = (const float*)d_in[9];
  const float* bout   = (const float*)d_in[10];

  float* out_hidd = (float*)d_out;
  float* out_logits = out_hidd + (size_t)Bb * Ss * Hh;

  float* ws = (float*)d_ws;
  float* s_buf = ws;                               // 2048
  float* e_buf = ws + 2048;                        // 2048
  float* zpref = ws + 4096;                        // 4*520
  float* zsuf  = ws + 4096 + 4 * ZLD;              // 4*520
  float* spart = ws + 8256;                        // 4*8*768
  float* xbuf  = ws + 32832;                       // 2048*768 fp32
  unsigned short* hbf  = (unsigned short*)(ws + 1605696);           // 2048*768 bf16
  unsigned short* xnbf = (unsigned short*)(ws + 1605696 + 786432);  // 2048*768 bf16
  unsigned short* wfcb = (unsigned short*)((char*)d_ws + 12714240); // 768*768 bf16
  unsigned short* woutb = (unsigned short*)((char*)d_ws + 13893888);// 30522*768 bf16
  const size_t need = 13893888 + (size_t)Vv * Hh * 2;               // ~60.8 MB

  const bool pre = ws_size >= need;

  k1_score<<<dim3(Bb * Ss / K1_TOK), dim3(256), 0, stream>>>(hidden, W1, b1, vat, s_buf);
  k15_pre<<<dim3(Bb), dim3(256), 0, stream>>>(s_buf, e_buf, zpref, zsuf);
  if (pre) {
    wconv<<<dim3(256), dim3(256), 0, stream>>>(Wfc, wfcb, Hh * Hh / 4);
    wconv<<<dim3(2048), dim3(256), 0, stream>>>(Wout, woutb, Vv * Hh / 4);
  }
  k2a_part<<<dim3(Bb * 8 * 3), dim3(256), 0, stream>>>(hidden, e_buf, spart);
  k2c_scan<<<dim3(Bb * 8 * 3), dim3(256), 0, stream>>>(hidden, e_buf, zpref, zsuf,
                                                       spart, ptype, out_hidd, hbf);
  if (pre) {
    gemm_bb<<<dim3((2048 / GBM) * (Hh / GBN)), dim3(256), 0, stream>>>(
        hbf, wfcb, bfc, xbuf, 2048, Hh, Hh, 2048 / GBM);
  } else {
    gemm_bt<<<dim3((2048 / GBM) * (Hh / GBN)), dim3(256), 0, stream>>>(
        hbf, Wfc, bfc, xbuf, 2048, Hh, Hh, 2048 / GBM);
  }
  k3b_geluln<<<dim3(2048), dim3(256), 0, stream>>>(xbuf, lng, lnb, xnbf);
  if (pre) {
    gemm8<<<dim3((2048 / 256) * ((Vv + 255) / 256)), dim3(512), 0, stream>>>(
        xnbf, woutb, bout, out_logits, 2048, Vv, Hh, 2048 / 256);
  } else {
    gemm_bt<<<dim3((2048 / GBM) * ((Vv + GBN - 1) / GBN)), dim3(256), 0, stream>>>(
        xnbf, Wout, bout, out_logits, 2048, Vv, Hh, 2048 / GBM);
  }
}

// Round 4
// 277.271 us; speedup vs baseline: 1.3027x; 1.3027x over previous
//
#include <hip/hip_runtime.h>
#include <math.h>

#define Bb 4
#define Ss 512
#define Hh 768
#define Vv 30522
#define Aa 200

typedef float f32x4 __attribute__((ext_vector_type(4)));
typedef short short8 __attribute__((ext_vector_type(8)));
typedef short short4v __attribute__((ext_vector_type(4)));
typedef __bf16 bf16x8 __attribute__((ext_vector_type(8)));

__device__ __forceinline__ unsigned short f2bf(float f) {
  union { float f; unsigned u; } v; v.f = f;
  unsigned r = v.u + 0x7FFFu + ((v.u >> 16) & 1u);
  return (unsigned short)(r >> 16);
}

__device__ __forceinline__ void gload16(const void* g, void* l) {
  __builtin_amdgcn_global_load_lds(
      (const __attribute__((address_space(1))) void*)g,
      (__attribute__((address_space(3))) void*)l, 16, 0, 0);
}

#define BAR()   do { asm volatile("" ::: "memory"); __builtin_amdgcn_s_barrier(); asm volatile("" ::: "memory"); } while(0)
#define LGKM0() do { asm volatile("s_waitcnt lgkmcnt(0)" ::: "memory"); __builtin_amdgcn_sched_barrier(0); } while(0)
#define VMW(n)  asm volatile("s_waitcnt vmcnt(" #n ")" ::: "memory")

// ---------------- K0: fp32 -> bf16 weight conversion -----------------------
__global__ __launch_bounds__(256) void wconv(
    const float* __restrict__ src, unsigned short* __restrict__ dst, int n4)
{
  int i = blockIdx.x * 256 + threadIdx.x;
  const int stride = gridDim.x * 256;
  for (; i < n4; i += stride) {
    f32x4 v = *reinterpret_cast<const f32x4*>(src + (size_t)i * 4);
    short4v p;
    #pragma unroll
    for (int q = 0; q < 4; ++q) p[q] = (short)f2bf(v[q]);
    *reinterpret_cast<short4v*>(dst + (size_t)i * 4) = p;
  }
}

// ---------------- K1: s[tok] = sum_a v_a * tanh(W1[a,:].h[tok] + b1[a]) ----
#define K1_TOK 8
__global__ __launch_bounds__(256) void k1_score(
    const float* __restrict__ hidden, const float* __restrict__ W1,
    const float* __restrict__ b1, const float* __restrict__ v_attn,
    float* __restrict__ s_buf)
{
  __shared__ float hsm[K1_TOK][Hh];
  __shared__ float part[K1_TOK][4];
  const int tid = threadIdx.x;
  const int tok0 = blockIdx.x * K1_TOK;
  #pragma unroll
  for (int i = 0; i < (K1_TOK * Hh / 4) / 256; ++i) {
    int c = i * 256 + tid;
    int row = c / (Hh / 4);
    int col4 = c % (Hh / 4);
    f32x4 v = *reinterpret_cast<const f32x4*>(hidden + (size_t)(tok0 + row) * Hh + col4 * 4);
    *reinterpret_cast<f32x4*>(&hsm[row][col4 * 4]) = v;
  }
  __syncthreads();
  float acc[K1_TOK];
  #pragma unroll
  for (int t = 0; t < K1_TOK; ++t) acc[t] = 0.f;
  if (tid < Aa) {
    const float* wr = W1 + (size_t)tid * Hh;
    for (int h = 0; h < Hh; h += 4) {
      f32x4 w4 = *reinterpret_cast<const f32x4*>(wr + h);
      #pragma unroll
      for (int t = 0; t < K1_TOK; ++t) {
        f32x4 h4 = *reinterpret_cast<const f32x4*>(&hsm[t][h]);
        acc[t] += w4[0]*h4[0] + w4[1]*h4[1] + w4[2]*h4[2] + w4[3]*h4[3];
      }
    }
  }
  const int lane = tid & 63, wv = tid >> 6;
  #pragma unroll
  for (int t = 0; t < K1_TOK; ++t) {
    float x = (tid < Aa) ? v_attn[tid] * tanhf(acc[t] + b1[tid]) : 0.f;
    #pragma unroll
    for (int o = 32; o > 0; o >>= 1) x += __shfl_xor(x, o);
    if (lane == 0) part[t][wv] = x;
  }
  __syncthreads();
  if (tid < K1_TOK)
    s_buf[tok0 + tid] = part[tid][0] + part[tid][1] + part[tid][2] + part[tid][3];
}

// ---------------- K1.5: per-batch e = exp(s-max), prefix + suffix sums -----
#define ZLD 520
__global__ __launch_bounds__(256) void k15_pre(
    const float* __restrict__ s_buf, float* __restrict__ e_buf,
    float* __restrict__ zpref, float* __restrict__ zsuf)
{
  const int b = blockIdx.x, tid = threadIdx.x;
  __shared__ float se[512];
  __shared__ float bA[512], bB[512];
  __shared__ float pm[4];
  float v0 = s_buf[b * 512 + tid], v1 = s_buf[b * 512 + 256 + tid];
  float m = fmaxf(v0, v1);
  #pragma unroll
  for (int o = 32; o > 0; o >>= 1) m = fmaxf(m, __shfl_xor(m, o));
  if ((tid & 63) == 0) pm[tid >> 6] = m;
  __syncthreads();
  float M = fmaxf(fmaxf(pm[0], pm[1]), fmaxf(pm[2], pm[3]));
  float e0 = expf(v0 - M), e1 = expf(v1 - M);
  se[tid] = e0; se[tid + 256] = e1;
  e_buf[b * 512 + tid] = e0; e_buf[b * 512 + 256 + tid] = e1;
  bA[tid] = e0; bA[tid + 256] = e1;
  __syncthreads();
  float* src = bA; float* dst = bB;
  for (int off = 1; off < 512; off <<= 1) {
    for (int i = tid; i < 512; i += 256)
      dst[i] = src[i] + ((i >= off) ? src[i - off] : 0.f);
    __syncthreads();
    float* t = src; src = dst; dst = t;
  }
  if (tid == 0) zpref[b * ZLD] = 0.f;
  zpref[b * ZLD + 1 + tid] = src[tid];
  zpref[b * ZLD + 257 + tid] = src[tid + 256];
  __syncthreads();
  src[tid] = se[tid]; src[tid + 256] = se[tid + 256];
  __syncthreads();
  for (int off = 1; off < 512; off <<= 1) {
    for (int i = tid; i < 512; i += 256)
      dst[i] = src[i] + ((i + off < 512) ? src[i + off] : 0.f);
    __syncthreads();
    float* t = src; src = dst; dst = t;
  }
  zsuf[b * ZLD + tid] = src[tid];
  zsuf[b * ZLD + 256 + tid] = src[tid + 256];
  if (tid == 0) zsuf[b * ZLD + 512] = 0.f;
}

// ---------------- K2a: per-16-chunk partial sums of e_k * h[k][f] ----------
// grid Bb*32*3, 16 iters/block (4x parallelism vs r3)
__global__ __launch_bounds__(256) void k2a_part(
    const float* __restrict__ hidden, const float* __restrict__ e_buf,
    float* __restrict__ spart)
{
  const int bid = blockIdx.x;
  const int fc = bid % 3, c = (bid / 3) % 32, b = bid / 96;
  const int f = fc * 256 + threadIdx.x;
  float acc = 0.f;
  #pragma unroll 4
  for (int kk = 0; kk < 16; ++kk) {
    int k = c * 16 + kk;
    acc += e_buf[b * 512 + k] * hidden[((size_t)(b * 512 + k)) * Hh + f];
  }
  spart[((size_t)b * 32 + c) * Hh + f] = acc;
}

// ---------------- K2c: scan -> hidd (fp32 to d_out, bf16 to ws) ------------
// grid Bb*16*3, 32 j per block (2x parallelism vs r3), chunks of 16
__global__ __launch_bounds__(256) void k2c_scan(
    const float* __restrict__ hidden, const float* __restrict__ e_buf,
    const float* __restrict__ zpref, const float* __restrict__ zsuf,
    const float* __restrict__ spart, const int* __restrict__ ptype,
    float* __restrict__ out_hidd, unsigned short* __restrict__ hbf)
{
  const int bid = blockIdx.x;
  const int fc = bid % 3, q = (bid / 3) % 16, b = bid / 48;
  const int f = fc * 256 + threadIdx.x;
  const int type = ptype[b];
  const float* Sp = spart + (size_t)b * 32 * Hh;
  const float* Zp = zpref + b * ZLD;
  const float* Zs = zsuf + b * ZLD;
  const size_t hbase = (size_t)b * 512 * Hh + f;
  const int j0 = q * 32;
  if (type == 0) {
    float run = 0.f;
    for (int c = 0; c < q * 2; ++c) run += Sp[c * Hh + f];
    for (int jj = 0; jj < 32; ++jj) {
      int j = j0 + jj;
      float ev = e_buf[b * 512 + j];
      float h = hidden[hbase + (size_t)j * Hh];
      run += ev * h;
      float val = run / (Zp[j + 1] * (float)(j + 1));
      out_hidd[hbase + (size_t)j * Hh] = val;
      hbf[hbase + (size_t)j * Hh] = f2bf(val);
    }
  } else if (type == 1) {
    float run = 0.f;
    for (int c = q * 2 + 2; c < 32; ++c) run += Sp[c * Hh + f];
    for (int jj = 31; jj >= 0; --jj) {
      int j = j0 + jj;
      float ev = e_buf[b * 512 + j];
      float h = hidden[hbase + (size_t)j * Hh];
      run += ev * h;
      float val = run / (Zs[j] * (float)(512 - j));
      out_hidd[hbase + (size_t)j * Hh] = val;
      hbf[hbase + (size_t)j * Hh] = f2bf(val);
    }
  } else {
    float T = 0.f;
    for (int c = 0; c < 32; ++c) T += Sp[c * Hh + f];
    float Ztot = Zp[512];
    for (int jj = 0; jj < 32; ++jj) {
      int j = j0 + jj;
      float ev = e_buf[b * 512 + j];
      float h = hidden[hbase + (size_t)j * Hh];
      float val = (T - ev * h) / ((Ztot - ev) * 511.0f);
      out_hidd[hbase + (size_t)j * Hh] = val;
      hbf[hbase + (size_t)j * Hh] = f2bf(val);
    }
  }
}

// ---------------- gemm8: 256x256 8-wave 4-phase pipelined bf16 GEMM --------
// Same K-loop as r3; NEW epilogue: stage C halves through LDS, then
// cooperative full-row f32x4 NON-TEMPORAL stores (full 128B lines, no L2
// pollution / partial-line writeback amplification).
__global__ __launch_bounds__(512, 2) void gemm8(
    const unsigned short* __restrict__ Abf, const unsigned short* __restrict__ Bbf,
    const float* __restrict__ bias, float* __restrict__ C,
    const int M, const int N, const int K, const int ntm)
{
  __shared__ __attribute__((aligned(16))) unsigned char lds8[131072];
  const int tid = threadIdx.x;
  const int total = gridDim.x;
  int bid = blockIdx.x;
  if ((total & 7) == 0) bid = (bid & 7) * (total >> 3) + (bid >> 3);  // XCD-chunked
  const int bm = bid % ntm;
  const int bn = bid / ntm;
  const int lane = tid & 63;
  const int wv = tid >> 6;
  const int wr = wv >> 2;
  const int wc = wv & 3;
  const int r15 = lane & 15, kg = lane >> 4;
  const int nt = K / 64;

  int ldso[2];
  size_t goffA[2][2], goffB[2][2];
  #pragma unroll
  for (int i = 0; i < 2; ++i) {
    int q = i * 512 + tid;
    int r = q >> 3, s = q & 7;
    int c = s ^ (r & 7);
    ldso[i] = q * 16;
    #pragma unroll
    for (int h = 0; h < 2; ++h) {
      int ra = bm * 256 + h * 128 + r;
      goffA[h][i] = (size_t)ra * K + c * 8;
      int rb = bn * 256 + h * 128 + r; if (rb >= N) rb = N - 1;
      goffB[h][i] = (size_t)rb * K + c * 8;
    }
  }
  const int slot0 = ((kg) ^ (r15 & 7)) * 16;
  const int slot1 = ((4 + kg) ^ (r15 & 7)) * 16;

#define STG_A(t, d) do { \
    unsigned char* lb_ = lds8 + (d) * 65536; \
    gload16(Abf + goffA[0][0] + (size_t)(t) * 64, lb_ + ldso[0]); \
    gload16(Abf + goffA[0][1] + (size_t)(t) * 64, lb_ + ldso[1]); \
    gload16(Abf + goffA[1][0] + (size_t)(t) * 64, lb_ + 16384 + ldso[0]); \
    gload16(Abf + goffA[1][1] + (size_t)(t) * 64, lb_ + 16384 + ldso[1]); \
  } while (0)
#define STG_B(t, h, d) do { \
    unsigned char* lb_ = lds8 + (d) * 65536 + 32768 + (h) * 16384; \
    gload16(Bbf + goffB[h][0] + (size_t)(t) * 64, lb_ + ldso[0]); \
    gload16(Bbf + goffB[h][1] + (size_t)(t) * 64, lb_ + ldso[1]); \
  } while (0)
#define RD_A(mg, d) do { \
    const unsigned char* ab_ = lds8 + (d) * 65536 + wr * 16384 + r15 * 128; \
    _Pragma("unroll") \
    for (int mm = 0; mm < 4; ++mm) { \
      af[mm * 2 + 0] = *reinterpret_cast<const bf16x8*>(ab_ + ((mg) * 4 + mm) * 2048 + slot0); \
      af[mm * 2 + 1] = *reinterpret_cast<const bf16x8*>(ab_ + ((mg) * 4 + mm) * 2048 + slot1); \
    } \
  } while (0)
#define RD_B(ng, d) do { \
    const unsigned char* bb_ = lds8 + (d) * 65536 + 32768 + (wc >> 1) * 16384 + ((wc & 1) * 64 + r15) * 128; \
    _Pragma("unroll") \
    for (int nn = 0; nn < 2; ++nn) { \
      bfr[((ng) * 2 + nn) * 2 + 0] = *reinterpret_cast<const bf16x8*>(bb_ + ((ng) * 2 + nn) * 2048 + slot0); \
      bfr[((ng) * 2 + nn) * 2 + 1] = *reinterpret_cast<const bf16x8*>(bb_ + ((ng) * 2 + nn) * 2048 + slot1); \
    } \
  } while (0)
#define MFMAQ(mg, ng) do { \
    _Pragma("unroll") \
    for (int mm = 0; mm < 4; ++mm) { \
      _Pragma("unroll") \
      for (int nn = 0; nn < 2; ++nn) { \
        const int n_ = (ng) * 2 + nn; \
        acc[(mg) * 4 + mm][n_] = __builtin_amdgcn_mfma_f32_16x16x32_bf16(af[mm * 2 + 0], bfr[n_ * 2 + 0], acc[(mg) * 4 + mm][n_], 0, 0, 0); \
        acc[(mg) * 4 + mm][n_] = __builtin_amdgcn_mfma_f32_16x16x32_bf16(af[mm * 2 + 1], bfr[n_ * 2 + 1], acc[(mg) * 4 + mm][n_], 0, 0, 0); \
      } \
    } \
  } while (0)

  f32x4 acc[8][4];
  #pragma unroll
  for (int m = 0; m < 8; ++m)
    #pragma unroll
    for (int n = 0; n < 4; ++n)
      #pragma unroll
      for (int r = 0; r < 4; ++r) acc[m][n][r] = 0.f;
  bf16x8 af[8], bfr[8];

  STG_A(0, 0);
  STG_B(0, 0, 0);
  STG_B(0, 1, 0);
  if (nt > 1) { STG_A(1, 1); VMW(4); } else { VMW(0); }
  BAR();

  for (int t = 0; t < nt; ++t) {
    const int cur = t & 1, nxt = cur ^ 1;
    RD_A(0, cur);
    RD_B(0, cur);
    if (t + 1 < nt) STG_B(t + 1, 0, nxt);
    BAR(); LGKM0();
    __builtin_amdgcn_s_setprio(1); MFMAQ(0, 0); __builtin_amdgcn_s_setprio(0);
    BAR();
    RD_B(1, cur);
    if (t + 1 < nt) STG_B(t + 1, 1, nxt);
    BAR(); LGKM0();
    __builtin_amdgcn_s_setprio(1); MFMAQ(0, 1); __builtin_amdgcn_s_setprio(0);
    BAR();
    RD_A(1, cur);
    BAR(); LGKM0();
    __builtin_amdgcn_s_setprio(1); MFMAQ(1, 0); __builtin_amdgcn_s_setprio(0);
    BAR();
    if (t + 2 < nt) STG_A(t + 2, cur);
    __builtin_amdgcn_s_setprio(1); MFMAQ(1, 1); __builtin_amdgcn_s_setprio(0);
    if (t + 2 < nt) { VMW(4); } else { VMW(0); }
    BAR();
  }

  // ---- epilogue: LDS-staged, coalesced non-temporal full-line stores ----
  float* ldsf = (float*)lds8;                    // [128][256] fp32 = 128 KB
  int nvt = N - bn * 256; if (nvt > 256) nvt = 256;
  const int nv = nvt;
  const int colc = (tid & 63) * 4;
  #pragma unroll
  for (int half = 0; half < 2; ++half) {
    BAR();
    if (wr == half) {
      #pragma unroll
      for (int n = 0; n < 4; ++n) {
        int colg = bn * 256 + wc * 64 + n * 16 + r15;
        float bv = (colg < N) ? bias[colg] : 0.f;
        int cloc = wc * 64 + n * 16 + r15;
        #pragma unroll
        for (int m = 0; m < 8; ++m) {
          int rloc = m * 16 + kg * 4;
          #pragma unroll
          for (int rr = 0; rr < 4; ++rr)
            ldsf[(rloc + rr) * 256 + cloc] = acc[m][n][rr] + bv;
        }
      }
    }
    BAR();
    const int rbase0 = bm * 256 + half * 128;
    if (colc < nv) {
      if (colc + 3 < nv) {
        for (int qq = 0; qq < 16; ++qq) {
          int row = qq * 8 + (tid >> 6);
          f32x4 v = *reinterpret_cast<const f32x4*>(&ldsf[row * 256 + colc]);
          __builtin_nontemporal_store(v,
              reinterpret_cast<f32x4*>(&C[(size_t)(rbase0 + row) * N + bn * 256 + colc]));
        }
      } else {
        for (int qq = 0; qq < 16; ++qq) {
          int row = qq * 8 + (tid >> 6);
          f32x4 v = *reinterpret_cast<const f32x4*>(&ldsf[row * 256 + colc]);
          size_t ga = (size_t)(rbase0 + row) * N + bn * 256 + colc;
          #pragma unroll
          for (int e = 0; e < 4; ++e)
            if (colc + e < nv) C[ga + e] = v[e];
        }
      }
    }
  }
#undef STG_A
#undef STG_B
#undef RD_A
#undef RD_B
#undef MFMAQ
}

// ---------------- gemm_bb (128x128): used for FC ---------------------------
#define GBM 128
#define GBN 128
#define GBK 64
__global__ __launch_bounds__(256) void gemm_bb(
    const unsigned short* __restrict__ Abf, const unsigned short* __restrict__ Bbf,
    const float* __restrict__ bias, float* __restrict__ C,
    const int M, const int N, const int K, const int ntm)
{
  __shared__ unsigned short As[GBM * GBK];
  __shared__ unsigned short Bs[GBN * GBK];
  const int tid = threadIdx.x;
  const int total = gridDim.x;
  int bid = blockIdx.x;
  if ((total & 7) == 0) bid = (bid & 7) * (total >> 3) + (bid >> 3);
  const int bm = bid % ntm;
  const int bn = bid / ntm;
  const int lane = tid & 63;
  const int wv = tid >> 6;
  const int wr = wv >> 1, wc = wv & 1;
  const int r15 = lane & 15, kg = lane >> 4;

  const unsigned short* ga[4];
  const unsigned short* gb[4];
  unsigned short* la[4];
  unsigned short* lb[4];
  #pragma unroll
  for (int i = 0; i < 4; ++i) {
    int qq = i * 256 + tid;
    int r = qq >> 3;
    int ks = (qq & 7) ^ (r & 7);
    ga[i] = Abf + (size_t)(bm * GBM + r) * K + ks * 8;
    int rowb = bn * GBN + r; rowb = rowb < N ? rowb : N - 1;
    gb[i] = Bbf + (size_t)rowb * K + ks * 8;
    la[i] = &As[qq * 8];
    lb[i] = &Bs[qq * 8];
  }

  f32x4 acc[4][4];
  #pragma unroll
  for (int m = 0; m < 4; ++m)
    #pragma unroll
    for (int n = 0; n < 4; ++n)
      #pragma unroll
      for (int r = 0; r < 4; ++r) acc[m][n][r] = 0.f;

  for (int kt = 0; kt < K; kt += GBK) {
    __syncthreads();
    #pragma unroll
    for (int i = 0; i < 4; ++i) gload16(ga[i] + kt, la[i]);
    #pragma unroll
    for (int i = 0; i < 4; ++i) gload16(gb[i] + kt, lb[i]);
    __syncthreads();
    #pragma unroll
    for (int kk = 0; kk < GBK / 32; ++kk) {
      bf16x8 af[4], bf[4];
      #pragma unroll
      for (int m = 0; m < 4; ++m) {
        int ra = wr * 64 + m * 16 + r15;
        int ck = ((kk << 2) | kg) ^ (ra & 7);
        af[m] = *reinterpret_cast<const bf16x8*>(&As[ra * GBK + ck * 8]);
      }
      #pragma unroll
      for (int n = 0; n < 4; ++n) {
        int rb = wc * 64 + n * 16 + r15;
        int ck = ((kk << 2) | kg) ^ (rb & 7);
        bf[n] = *reinterpret_cast<const bf16x8*>(&Bs[rb * GBK + ck * 8]);
      }
      #pragma unroll
      for (int m = 0; m < 4; ++m)
        #pragma unroll
        for (int n = 0; n < 4; ++n)
          acc[m][n] = __builtin_amdgcn_mfma_f32_16x16x32_bf16(af[m], bf[n], acc[m][n], 0, 0, 0);
    }
  }
  #pragma unroll
  for (int n = 0; n < 4; ++n) {
    int col = bn * GBN + wc * 64 + n * 16 + r15;
    if (col < N) {
      float bv = bias[col];
      #pragma unroll
      for (int m = 0; m < 4; ++m) {
        int rbase = bm * GBM + wr * 64 + m * 16 + kg * 4;
        #pragma unroll
        for (int r = 0; r < 4; ++r)
          C[(size_t)(rbase + r) * N + col] = acc[m][n][r] + bv;
      }
    }
  }
}

// ---------------- fallback GEMM (fp32 B, on-the-fly convert) ---------------
__global__ __launch_bounds__(256) void gemm_bt(
    const unsigned short* __restrict__ Abf, const float* __restrict__ Bsrc,
    const float* __restrict__ bias, float* __restrict__ C,
    const int M, const int N, const int K, const int ntm)
{
  __shared__ unsigned short As[GBM * GBK];
  __shared__ unsigned short Bs[GBN * GBK];
  const int tid = threadIdx.x;
  const int total = gridDim.x;
  int bid = blockIdx.x;
  if ((total & 7) == 0) bid = (bid & 7) * (total >> 3) + (bid >> 3);
  const int bm = bid % ntm;
  const int bn = bid / ntm;
  const int lane = tid & 63;
  const int wv = tid >> 6;
  const int wr = wv >> 1, wc = wv & 1;
  const int r15 = lane & 15, kg = lane >> 4;

  f32x4 acc[4][4];
  #pragma unroll
  for (int m = 0; m < 4; ++m)
    #pragma unroll
    for (int n = 0; n < 4; ++n)
      #pragma unroll
      for (int r = 0; r < 4; ++r) acc[m][n][r] = 0.f;

  for (int kt = 0; kt < K; kt += GBK) {
    __syncthreads();
    #pragma unroll
    for (int i = 0; i < 4; ++i) {
      int c = i * 256 + tid;
      int row = c >> 3, col8 = c & 7;
      short8 v = *reinterpret_cast<const short8*>(Abf + (size_t)(bm * GBM + row) * K + kt + col8 * 8);
      int idx = (row * GBK + col8 * 8) ^ ((row & 7) << 3);
      *reinterpret_cast<short8*>(&As[idx]) = v;
    }
    #pragma unroll
    for (int i = 0; i < 8; ++i) {
      int c = i * 256 + tid;
      int row = c >> 4, col4 = c & 15;
      int nsrc = bn * GBN + row; nsrc = nsrc < N ? nsrc : N - 1;
      f32x4 v = *reinterpret_cast<const f32x4*>(Bsrc + (size_t)nsrc * K + kt + col4 * 4);
      short4v p;
      #pragma unroll
      for (int q = 0; q < 4; ++q) p[q] = (short)f2bf(v[q]);
      int idx = (row * GBK + col4 * 4) ^ ((row & 7) << 3);
      *reinterpret_cast<short4v*>(&Bs[idx]) = p;
    }
    __syncthreads();
    #pragma unroll
    for (int kk = 0; kk < GBK / 32; ++kk) {
      bf16x8 af[4], bf[4];
      #pragma unroll
      for (int m = 0; m < 4; ++m) {
        int row = wr * 64 + m * 16 + r15;
        int col = kk * 32 + kg * 8;
        af[m] = *reinterpret_cast<const bf16x8*>(&As[(row * GBK + col) ^ ((row & 7) << 3)]);
      }
      #pragma unroll
      for (int n = 0; n < 4; ++n) {
        int row = wc * 64 + n * 16 + r15;
        int col = kk * 32 + kg * 8;
        bf[n] = *reinterpret_cast<const bf16x8*>(&Bs[(row * GBK + col) ^ ((row & 7) << 3)]);
      }
      #pragma unroll
      for (int m = 0; m < 4; ++m)
        #pragma unroll
        for (int n = 0; n < 4; ++n)
          acc[m][n] = __builtin_amdgcn_mfma_f32_16x16x32_bf16(af[m], bf[n], acc[m][n], 0, 0, 0);
    }
  }
  #pragma unroll
  for (int n = 0; n < 4; ++n) {
    int col = bn * GBN + wc * 64 + n * 16 + r15;
    if (col < N) {
      float bv = bias[col];
      #pragma unroll
      for (int m = 0; m < 4; ++m) {
        int rbase = bm * GBM + wr * 64 + m * 16 + kg * 4;
        #pragma unroll
        for (int r = 0; r < 4; ++r)
          C[(size_t)(rbase + r) * N + col] = acc[m][n][r] + bv;
      }
    }
  }
}

// ---------------- K3b: exact GELU + LayerNorm -> xn (bf16) -----------------
__global__ __launch_bounds__(256) void k3b_geluln(
    const float* __restrict__ x, const float* __restrict__ gam,
    const float* __restrict__ bet, unsigned short* __restrict__ xnbf)
{
  const int row = blockIdx.x, tid = threadIdx.x;
  __shared__ float part[4];
  float g[3];
  float s = 0.f;
  #pragma unroll
  for (int i = 0; i < 3; ++i) {
    float xv = x[(size_t)row * Hh + tid + 256 * i];
    float t = 0.5f * xv * (1.f + erff(xv * 0.70710678118654752f));
    g[i] = t; s += t;
  }
  #pragma unroll
  for (int o = 32; o > 0; o >>= 1) s += __shfl_xor(s, o);
  if ((tid & 63) == 0) part[tid >> 6] = s;
  __syncthreads();
  float mu = (part[0] + part[1] + part[2] + part[3]) * (1.f / 768.f);
  __syncthreads();
  float vs = 0.f;
  #pragma unroll
  for (int i = 0; i < 3; ++i) { float d = g[i] - mu; vs += d * d; }
  #pragma unroll
  for (int o = 32; o > 0; o >>= 1) vs += __shfl_xor(vs, o);
  if ((tid & 63) == 0) part[tid >> 6] = vs;
  __syncthreads();
  float var = (part[0] + part[1] + part[2] + part[3]) * (1.f / 768.f);
  float inv = 1.0f / sqrtf(var + 1e-12f);
  #pragma unroll
  for (int i = 0; i < 3; ++i) {
    int f = tid + 256 * i;
    xnbf[(size_t)row * Hh + f] = f2bf((g[i] - mu) * inv * gam[f] + bet[f]);
  }
}

extern "C" void kernel_launch(void* const* d_in, const int* in_sizes, int n_in,
                              void* d_out, int out_size, void* d_ws, size_t ws_size,
                              hipStream_t stream)
{
  const float* hidden = (const float*)d_in[0];
  const int*   ptype  = (const int*)d_in[1];
  const float* W1     = (const float*)d_in[2];
  const float* b1     = (const float*)d_in[3];
  const float* vat    = (const float*)d_in[4];
  const float* Wfc    = (const float*)d_in[5];
  const float* bfc    = (const float*)d_in[6];
  const float* lng    = (const float*)d_in[7];
  const float* lnb    = (const float*)d_in[8];
  const float* Wout   = (const float*)d_in[9];
  const float* bout   = (const float*)d_in[10];

  float* out_hidd = (float*)d_out;
  float* out_logits = out_hidd + (size_t)Bb * Ss * Hh;

  // workspace layout (float offsets); xnbf reuses hbf (dead after FC GEMM)
  float* ws = (float*)d_ws;
  float* s_buf = ws;                                   // [0, 2048)
  float* e_buf = ws + 2048;                            // [2048, 4096)
  float* zpref = ws + 4096;                            // [4096, 6176)
  float* zsuf  = ws + 6176;                            // [6176, 8256)
  float* xbuf  = ws + 8256;                            // [8256, 1581120)
  float* spart = ws + 1581120;                         // [1581120, 1679424) 4*32*768
  unsigned short* hbf  = (unsigned short*)(ws + 1679424);   // 2048*768 bf16
  unsigned short* xnbf = hbf;                               // reuse (hbf dead)
  unsigned short* wfcb = (unsigned short*)(ws + 2465856);   // 768*768 bf16
  unsigned short* woutb = (unsigned short*)(ws + 2760768);  // 30522*768 bf16
  const size_t need = (size_t)2760768 * 4 + (size_t)Vv * Hh * 2;  // ~57.9 MB

  const bool pre = ws_size >= need;

  k1_score<<<dim3(Bb * Ss / K1_TOK), dim3(256), 0, stream>>>(hidden, W1, b1, vat, s_buf);
  k15_pre<<<dim3(Bb), dim3(256), 0, stream>>>(s_buf, e_buf, zpref, zsuf);
  if (pre) {
    wconv<<<dim3(256), dim3(256), 0, stream>>>(Wfc, wfcb, Hh * Hh / 4);
    wconv<<<dim3(2048), dim3(256), 0, stream>>>(Wout, woutb, Vv * Hh / 4);
  }
  k2a_part<<<dim3(Bb * 32 * 3), dim3(256), 0, stream>>>(hidden, e_buf, spart);
  k2c_scan<<<dim3(Bb * 16 * 3), dim3(256), 0, stream>>>(hidden, e_buf, zpref, zsuf,
                                                        spart, ptype, out_hidd, hbf);
  if (pre) {
    gemm_bb<<<dim3((2048 / GBM) * (Hh / GBN)), dim3(256), 0, stream>>>(
        hbf, wfcb, bfc, xbuf, 2048, Hh, Hh, 2048 / GBM);
  } else {
    gemm_bt<<<dim3((2048 / GBM) * (Hh / GBN)), dim3(256), 0, stream>>>(
        hbf, Wfc, bfc, xbuf, 2048, Hh, Hh, 2048 / GBM);
  }
  k3b_geluln<<<dim3(2048), dim3(256), 0, stream>>>(xbuf, lng, lnb, xnbf);
  if (pre) {
    gemm8<<<dim3((2048 / 256) * ((Vv + 255) / 256)), dim3(512), 0, stream>>>(
        xnbf, woutb, bout, out_logits, 2048, Vv, Hh, 2048 / 256);
  } else {
    gemm_bt<<<dim3((2048 / GBM) * ((Vv + GBN - 1) / GBN)), dim3(256), 0, stream>>>(
        xnbf, Wout, bout, out_logits, 2048, Vv, Hh, 2048 / GBM);
  }
}

// Round 5
// 256.687 us; speedup vs baseline: 1.4071x; 1.0802x over previous
//
#include <hip/hip_runtime.h>
#include <math.h>

#define Bb 4
#define Ss 512
#define Hh 768
#define Vv 30522
#define Aa 200

typedef float f32x4 __attribute__((ext_vector_type(4)));
typedef short short8 __attribute__((ext_vector_type(8)));
typedef short short4v __attribute__((ext_vector_type(4)));
typedef __bf16 bf16x8 __attribute__((ext_vector_type(8)));

__device__ __forceinline__ unsigned short f2bf(float f) {
  union { float f; unsigned u; } v; v.f = f;
  unsigned r = v.u + 0x7FFFu + ((v.u >> 16) & 1u);
  return (unsigned short)(r >> 16);
}

__device__ __forceinline__ void gload16(const void* g, void* l) {
  __builtin_amdgcn_global_load_lds(
      (const __attribute__((address_space(1))) void*)g,
      (__attribute__((address_space(3))) void*)l, 16, 0, 0);
}

#define BAR()   do { asm volatile("" ::: "memory"); __builtin_amdgcn_s_barrier(); asm volatile("" ::: "memory"); } while(0)
#define LGKM0() do { asm volatile("s_waitcnt lgkmcnt(0)" ::: "memory"); __builtin_amdgcn_sched_barrier(0); } while(0)
#define VMW(n)  asm volatile("s_waitcnt vmcnt(" #n ")" ::: "memory")

// ---------------- K0: fp32 -> bf16 weight conversion -----------------------
__global__ __launch_bounds__(256) void wconv(
    const float* __restrict__ src, unsigned short* __restrict__ dst, int n4)
{
  int i = blockIdx.x * 256 + threadIdx.x;
  const int stride = gridDim.x * 256;
  for (; i < n4; i += stride) {
    f32x4 v = *reinterpret_cast<const f32x4*>(src + (size_t)i * 4);
    short4v p;
    #pragma unroll
    for (int q = 0; q < 4; ++q) p[q] = (short)f2bf(v[q]);
    *reinterpret_cast<short4v*>(dst + (size_t)i * 4) = p;
  }
}

// ---------------- K1: s[tok] = sum_a v_a * tanh(W1[a,:].h[tok] + b1[a]) ----
#define K1_TOK 8
__global__ __launch_bounds__(256) void k1_score(
    const float* __restrict__ hidden, const float* __restrict__ W1,
    const float* __restrict__ b1, const float* __restrict__ v_attn,
    float* __restrict__ s_buf)
{
  __shared__ float hsm[K1_TOK][Hh];
  __shared__ float part[K1_TOK][4];
  const int tid = threadIdx.x;
  const int tok0 = blockIdx.x * K1_TOK;
  #pragma unroll
  for (int i = 0; i < (K1_TOK * Hh / 4) / 256; ++i) {
    int c = i * 256 + tid;
    int row = c / (Hh / 4);
    int col4 = c % (Hh / 4);
    f32x4 v = *reinterpret_cast<const f32x4*>(hidden + (size_t)(tok0 + row) * Hh + col4 * 4);
    *reinterpret_cast<f32x4*>(&hsm[row][col4 * 4]) = v;
  }
  __syncthreads();
  float acc[K1_TOK];
  #pragma unroll
  for (int t = 0; t < K1_TOK; ++t) acc[t] = 0.f;
  if (tid < Aa) {
    const float* wr = W1 + (size_t)tid * Hh;
    for (int h = 0; h < Hh; h += 4) {
      f32x4 w4 = *reinterpret_cast<const f32x4*>(wr + h);
      #pragma unroll
      for (int t = 0; t < K1_TOK; ++t) {
        f32x4 h4 = *reinterpret_cast<const f32x4*>(&hsm[t][h]);
        acc[t] += w4[0]*h4[0] + w4[1]*h4[1] + w4[2]*h4[2] + w4[3]*h4[3];
      }
    }
  }
  const int lane = tid & 63, wv = tid >> 6;
  #pragma unroll
  for (int t = 0; t < K1_TOK; ++t) {
    float x = (tid < Aa) ? v_attn[tid] * tanhf(acc[t] + b1[tid]) : 0.f;
    #pragma unroll
    for (int o = 32; o > 0; o >>= 1) x += __shfl_xor(x, o);
    if (lane == 0) part[t][wv] = x;
  }
  __syncthreads();
  if (tid < K1_TOK)
    s_buf[tok0 + tid] = part[tid][0] + part[tid][1] + part[tid][2] + part[tid][3];
}

// ---------------- K1.5: per-batch e = exp(s-max), prefix + suffix sums -----
#define ZLD 520
__global__ __launch_bounds__(256) void k15_pre(
    const float* __restrict__ s_buf, float* __restrict__ e_buf,
    float* __restrict__ zpref, float* __restrict__ zsuf)
{
  const int b = blockIdx.x, tid = threadIdx.x;
  __shared__ float se[512];
  __shared__ float bA[512], bB[512];
  __shared__ float pm[4];
  float v0 = s_buf[b * 512 + tid], v1 = s_buf[b * 512 + 256 + tid];
  float m = fmaxf(v0, v1);
  #pragma unroll
  for (int o = 32; o > 0; o >>= 1) m = fmaxf(m, __shfl_xor(m, o));
  if ((tid & 63) == 0) pm[tid >> 6] = m;
  __syncthreads();
  float M = fmaxf(fmaxf(pm[0], pm[1]), fmaxf(pm[2], pm[3]));
  float e0 = expf(v0 - M), e1 = expf(v1 - M);
  se[tid] = e0; se[tid + 256] = e1;
  e_buf[b * 512 + tid] = e0; e_buf[b * 512 + 256 + tid] = e1;
  bA[tid] = e0; bA[tid + 256] = e1;
  __syncthreads();
  float* src = bA; float* dst = bB;
  for (int off = 1; off < 512; off <<= 1) {
    for (int i = tid; i < 512; i += 256)
      dst[i] = src[i] + ((i >= off) ? src[i - off] : 0.f);
    __syncthreads();
    float* t = src; src = dst; dst = t;
  }
  if (tid == 0) zpref[b * ZLD] = 0.f;
  zpref[b * ZLD + 1 + tid] = src[tid];
  zpref[b * ZLD + 257 + tid] = src[tid + 256];
  __syncthreads();
  src[tid] = se[tid]; src[tid + 256] = se[tid + 256];
  __syncthreads();
  for (int off = 1; off < 512; off <<= 1) {
    for (int i = tid; i < 512; i += 256)
      dst[i] = src[i] + ((i + off < 512) ? src[i + off] : 0.f);
    __syncthreads();
    float* t = src; src = dst; dst = t;
  }
  zsuf[b * ZLD + tid] = src[tid];
  zsuf[b * ZLD + 256 + tid] = src[tid + 256];
  if (tid == 0) zsuf[b * ZLD + 512] = 0.f;
}

// ---------------- K2a: per-16-chunk partial sums of e_k * h[k][f] ----------
__global__ __launch_bounds__(256) void k2a_part(
    const float* __restrict__ hidden, const float* __restrict__ e_buf,
    float* __restrict__ spart)
{
  const int bid = blockIdx.x;
  const int fc = bid % 3, c = (bid / 3) % 32, b = bid / 96;
  const int f = fc * 256 + threadIdx.x;
  float acc = 0.f;
  #pragma unroll 4
  for (int kk = 0; kk < 16; ++kk) {
    int k = c * 16 + kk;
    acc += e_buf[b * 512 + k] * hidden[((size_t)(b * 512 + k)) * Hh + f];
  }
  spart[((size_t)b * 32 + c) * Hh + f] = acc;
}

// ---------------- K2c: scan -> hidd (fp32 to d_out, bf16 to ws) ------------
__global__ __launch_bounds__(256) void k2c_scan(
    const float* __restrict__ hidden, const float* __restrict__ e_buf,
    const float* __restrict__ zpref, const float* __restrict__ zsuf,
    const float* __restrict__ spart, const int* __restrict__ ptype,
    float* __restrict__ out_hidd, unsigned short* __restrict__ hbf)
{
  const int bid = blockIdx.x;
  const int fc = bid % 3, q = (bid / 3) % 16, b = bid / 48;
  const int f = fc * 256 + threadIdx.x;
  const int type = ptype[b];
  const float* Sp = spart + (size_t)b * 32 * Hh;
  const float* Zp = zpref + b * ZLD;
  const float* Zs = zsuf + b * ZLD;
  const size_t hbase = (size_t)b * 512 * Hh + f;
  const int j0 = q * 32;
  if (type == 0) {
    float run = 0.f;
    for (int c = 0; c < q * 2; ++c) run += Sp[c * Hh + f];
    for (int jj = 0; jj < 32; ++jj) {
      int j = j0 + jj;
      float ev = e_buf[b * 512 + j];
      float h = hidden[hbase + (size_t)j * Hh];
      run += ev * h;
      float val = run / (Zp[j + 1] * (float)(j + 1));
      out_hidd[hbase + (size_t)j * Hh] = val;
      hbf[hbase + (size_t)j * Hh] = f2bf(val);
    }
  } else if (type == 1) {
    float run = 0.f;
    for (int c = q * 2 + 2; c < 32; ++c) run += Sp[c * Hh + f];
    for (int jj = 31; jj >= 0; --jj) {
      int j = j0 + jj;
      float ev = e_buf[b * 512 + j];
      float h = hidden[hbase + (size_t)j * Hh];
      run += ev * h;
      float val = run / (Zs[j] * (float)(512 - j));
      out_hidd[hbase + (size_t)j * Hh] = val;
      hbf[hbase + (size_t)j * Hh] = f2bf(val);
    }
  } else {
    float T = 0.f;
    for (int c = 0; c < 32; ++c) T += Sp[c * Hh + f];
    float Ztot = Zp[512];
    for (int jj = 0; jj < 32; ++jj) {
      int j = j0 + jj;
      float ev = e_buf[b * 512 + j];
      float h = hidden[hbase + (size_t)j * Hh];
      float val = (T - ev * h) / ((Ztot - ev) * 511.0f);
      out_hidd[hbase + (size_t)j * Hh] = val;
      hbf[hbase + (size_t)j * Hh] = f2bf(val);
    }
  }
}

// ---------------- gemm4: 128x128 4-wave BK=32 pipelined bf16 GEMM ----------
// Wave-tile 64x64 (acc=64 regs) + __launch_bounds__(256,4) -> total regs <=128
// -> 4 blocks/CU: cross-block overlap covers barriers, vmcnt waits, and the
// epilogue store drain (stores/loads share one per-wave vmcnt queue, so
// overlap MUST come from other resident blocks).
// LDS stripe-granule layout (conflict-free, lane-linear for global_load_lds):
//   granule(r,c) -> byte (r>>4)*1024 + (r&15)*64 + c*16   [r:row, c:k-octet]
// Each ds_read_b128 fragment sweep (lane=(r15,kg)) reads a dense 1KB stripe.
// Schedule per K-step t (cur = t&1):
//   phA: RD all 8 frags <- cur; BAR; LGKM0; MFMA m0-1 (8); BAR.
//   phB: STG A/B(t+2) -> cur (region dead after phA's barrier);
//        MFMA m2-3 (8); VMW(4) [leaves only t+2's 4 loads in flight]; BAR.
__global__ __launch_bounds__(256, 4) void gemm4(
    const unsigned short* __restrict__ Abf, const unsigned short* __restrict__ Bbf,
    const float* __restrict__ bias, float* __restrict__ C,
    const int M, const int N, const int K, const int ntm)
{
  __shared__ __attribute__((aligned(16))) unsigned char lds[32768];
  const int tid = threadIdx.x;
  const int total = gridDim.x;
  int bid = blockIdx.x;
  if ((total & 7) == 0) bid = (bid & 7) * (total >> 3) + (bid >> 3);  // XCD-chunked
  const int bm = bid % ntm;          // bn-major within chunk: B-panel L2-hot
  const int bn = bid / ntm;
  const int lane = tid & 63;
  const int wv = tid >> 6;           // 0..3
  const int wr = wv >> 1;            // 0..1 -> rows wr*64
  const int wc = wv & 1;             // 0..1 -> cols wc*64
  const int r15 = lane & 15, kg = lane >> 4;
  const int nt = K / 32;

  // staging geometry: thread stages granules g = i*256+tid (i=0,1) of A and B
  unsigned offA[2], offB[2];
  int ldsg[2];
  #pragma unroll
  for (int i = 0; i < 2; ++i) {
    int g = i * 256 + tid;
    int r = ((g >> 6) << 4) | ((g >> 2) & 15);
    int c = g & 3;
    offA[i] = (unsigned)((bm * 128 + r) * K + c * 8);
    int rb = bn * 128 + r; if (rb >= N) rb = N - 1;
    offB[i] = (unsigned)(rb * K + c * 8);
    ldsg[i] = g * 16;
  }

#define STG(t, d) do { \
    unsigned char* lb_ = lds + (d) * 16384; \
    gload16(Abf + offA[0] + (t) * 32, lb_ + ldsg[0]); \
    gload16(Abf + offA[1] + (t) * 32, lb_ + ldsg[1]); \
    gload16(Bbf + offB[0] + (t) * 32, lb_ + 8192 + ldsg[0]); \
    gload16(Bbf + offB[1] + (t) * 32, lb_ + 8192 + ldsg[1]); \
  } while (0)
#define RDALL(d) do { \
    const unsigned char* ab_ = lds + (d) * 16384 + wr * 4096 + r15 * 64 + kg * 16; \
    af[0] = *reinterpret_cast<const bf16x8*>(ab_); \
    af[1] = *reinterpret_cast<const bf16x8*>(ab_ + 1024); \
    af[2] = *reinterpret_cast<const bf16x8*>(ab_ + 2048); \
    af[3] = *reinterpret_cast<const bf16x8*>(ab_ + 3072); \
    const unsigned char* bb_ = lds + (d) * 16384 + 8192 + wc * 4096 + r15 * 64 + kg * 16; \
    bfr[0] = *reinterpret_cast<const bf16x8*>(bb_); \
    bfr[1] = *reinterpret_cast<const bf16x8*>(bb_ + 1024); \
    bfr[2] = *reinterpret_cast<const bf16x8*>(bb_ + 2048); \
    bfr[3] = *reinterpret_cast<const bf16x8*>(bb_ + 3072); \
  } while (0)
#define MFH(m0) do { \
    _Pragma("unroll") \
    for (int mm = (m0); mm < (m0) + 2; ++mm) { \
      _Pragma("unroll") \
      for (int nn = 0; nn < 4; ++nn) \
        acc[mm][nn] = __builtin_amdgcn_mfma_f32_16x16x32_bf16(af[mm], bfr[nn], acc[mm][nn], 0, 0, 0); \
    } \
  } while (0)

  f32x4 acc[4][4];
  #pragma unroll
  for (int m = 0; m < 4; ++m)
    #pragma unroll
    for (int n = 0; n < 4; ++n)
      #pragma unroll
      for (int r = 0; r < 4; ++r) acc[m][n][r] = 0.f;
  bf16x8 af[4], bfr[4];

  // prologue: tiles 0 and 1; wait tile 0 landed (tile 1 stays in flight)
  STG(0, 0);
  STG(1, 1);
  VMW(4);
  BAR();

  for (int t = 0; t < nt; ++t) {
    const int cur = t & 1;
    // phA
    RDALL(cur);
    BAR(); LGKM0();
    __builtin_amdgcn_s_setprio(1); MFH(0); __builtin_amdgcn_s_setprio(0);
    BAR();
    // phB
    if (t + 2 < nt) STG(t + 2, cur);
    __builtin_amdgcn_s_setprio(1); MFH(2); __builtin_amdgcn_s_setprio(0);
    if (t + 2 < nt) { VMW(4); } else { VMW(0); }
    BAR();
  }

  // ---- epilogue: LDS-staged, coalesced non-temporal full-line stores ----
  float* ldsf = (float*)lds;                    // [64][128] fp32 = 32 KB
  int nvt = N - bn * 128; if (nvt > 128) nvt = 128;
  const int nv = nvt;
  const int colc = (tid & 31) * 4;
  const int rsub = tid >> 5;                    // 0..7
  #pragma unroll
  for (int half = 0; half < 2; ++half) {
    BAR();
    if (wr == half) {
      #pragma unroll
      for (int n = 0; n < 4; ++n) {
        int colg = bn * 128 + wc * 64 + n * 16 + r15;
        float bv = (colg < N) ? bias[colg] : 0.f;
        int cloc = wc * 64 + n * 16 + r15;
        #pragma unroll
        for (int m = 0; m < 4; ++m) {
          int rloc = m * 16 + kg * 4;
          #pragma unroll
          for (int rr = 0; rr < 4; ++rr)
            ldsf[(rloc + rr) * 128 + cloc] = acc[m][n][rr] + bv;
        }
      }
    }
    BAR();
    const int rbase0 = bm * 128 + half * 64;
    if (colc < nv) {
      if (colc + 3 < nv) {
        #pragma unroll
        for (int qq = 0; qq < 8; ++qq) {
          int row = qq * 8 + rsub;
          f32x4 v = *reinterpret_cast<const f32x4*>(&ldsf[row * 128 + colc]);
          __builtin_nontemporal_store(v,
              reinterpret_cast<f32x4*>(&C[(size_t)(rbase0 + row) * N + bn * 128 + colc]));
        }
      } else {
        for (int qq = 0; qq < 8; ++qq) {
          int row = qq * 8 + rsub;
          f32x4 v = *reinterpret_cast<const f32x4*>(&ldsf[row * 128 + colc]);
          size_t ga = (size_t)(rbase0 + row) * N + bn * 128 + colc;
          #pragma unroll
          for (int e = 0; e < 4; ++e)
            if (colc + e < nv) C[ga + e] = v[e];
        }
      }
    }
  }
#undef STG
#undef RDALL
#undef MFH
}

// ---------------- fallback GEMM (fp32 B, on-the-fly convert) ---------------
#define GBM 128
#define GBN 128
#define GBK 64
__global__ __launch_bounds__(256) void gemm_bt(
    const unsigned short* __restrict__ Abf, const float* __restrict__ Bsrc,
    const float* __restrict__ bias, float* __restrict__ C,
    const int M, const int N, const int K, const int ntm)
{
  __shared__ unsigned short As[GBM * GBK];
  __shared__ unsigned short Bs[GBN * GBK];
  const int tid = threadIdx.x;
  const int total = gridDim.x;
  int bid = blockIdx.x;
  if ((total & 7) == 0) bid = (bid & 7) * (total >> 3) + (bid >> 3);
  const int bm = bid % ntm;
  const int bn = bid / ntm;
  const int lane = tid & 63;
  const int wv = tid >> 6;
  const int wr = wv >> 1, wc = wv & 1;
  const int r15 = lane & 15, kg = lane >> 4;

  f32x4 acc[4][4];
  #pragma unroll
  for (int m = 0; m < 4; ++m)
    #pragma unroll
    for (int n = 0; n < 4; ++n)
      #pragma unroll
      for (int r = 0; r < 4; ++r) acc[m][n][r] = 0.f;

  for (int kt = 0; kt < K; kt += GBK) {
    __syncthreads();
    #pragma unroll
    for (int i = 0; i < 4; ++i) {
      int c = i * 256 + tid;
      int row = c >> 3, col8 = c & 7;
      short8 v = *reinterpret_cast<const short8*>(Abf + (size_t)(bm * GBM + row) * K + kt + col8 * 8);
      int idx = (row * GBK + col8 * 8) ^ ((row & 7) << 3);
      *reinterpret_cast<short8*>(&As[idx]) = v;
    }
    #pragma unroll
    for (int i = 0; i < 8; ++i) {
      int c = i * 256 + tid;
      int row = c >> 4, col4 = c & 15;
      int nsrc = bn * GBN + row; nsrc = nsrc < N ? nsrc : N - 1;
      f32x4 v = *reinterpret_cast<const f32x4*>(Bsrc + (size_t)nsrc * K + kt + col4 * 4);
      short4v p;
      #pragma unroll
      for (int q = 0; q < 4; ++q) p[q] = (short)f2bf(v[q]);
      int idx = (row * GBK + col4 * 4) ^ ((row & 7) << 3);
      *reinterpret_cast<short4v*>(&Bs[idx]) = p;
    }
    __syncthreads();
    #pragma unroll
    for (int kk = 0; kk < GBK / 32; ++kk) {
      bf16x8 af[4], bf[4];
      #pragma unroll
      for (int m = 0; m < 4; ++m) {
        int row = wr * 64 + m * 16 + r15;
        int col = kk * 32 + kg * 8;
        af[m] = *reinterpret_cast<const bf16x8*>(&As[(row * GBK + col) ^ ((row & 7) << 3)]);
      }
      #pragma unroll
      for (int n = 0; n < 4; ++n) {
        int row = wc * 64 + n * 16 + r15;
        int col = kk * 32 + kg * 8;
        bf[n] = *reinterpret_cast<const bf16x8*>(&Bs[(row * GBK + col) ^ ((row & 7) << 3)]);
      }
      #pragma unroll
      for (int m = 0; m < 4; ++m)
        #pragma unroll
        for (int n = 0; n < 4; ++n)
          acc[m][n] = __builtin_amdgcn_mfma_f32_16x16x32_bf16(af[m], bf[n], acc[m][n], 0, 0, 0);
    }
  }
  #pragma unroll
  for (int n = 0; n < 4; ++n) {
    int col = bn * GBN + wc * 64 + n * 16 + r15;
    if (col < N) {
      float bv = bias[col];
      #pragma unroll
      for (int m = 0; m < 4; ++m) {
        int rbase = bm * GBM + wr * 64 + m * 16 + kg * 4;
        #pragma unroll
        for (int r = 0; r < 4; ++r)
          C[(size_t)(rbase + r) * N + col] = acc[m][n][r] + bv;
      }
    }
  }
}

// ---------------- K3b: exact GELU + LayerNorm -> xn (bf16) -----------------
__global__ __launch_bounds__(256) void k3b_geluln(
    const float* __restrict__ x, const float* __restrict__ gam,
    const float* __restrict__ bet, unsigned short* __restrict__ xnbf)
{
  const int row = blockIdx.x, tid = threadIdx.x;
  __shared__ float part[4];
  float g[3];
  float s = 0.f;
  #pragma unroll
  for (int i = 0; i < 3; ++i) {
    float xv = x[(size_t)row * Hh + tid + 256 * i];
    float t = 0.5f * xv * (1.f + erff(xv * 0.70710678118654752f));
    g[i] = t; s += t;
  }
  #pragma unroll
  for (int o = 32; o > 0; o >>= 1) s += __shfl_xor(s, o);
  if ((tid & 63) == 0) part[tid >> 6] = s;
  __syncthreads();
  float mu = (part[0] + part[1] + part[2] + part[3]) * (1.f / 768.f);
  __syncthreads();
  float vs = 0.f;
  #pragma unroll
  for (int i = 0; i < 3; ++i) { float d = g[i] - mu; vs += d * d; }
  #pragma unroll
  for (int o = 32; o > 0; o >>= 1) vs += __shfl_xor(vs, o);
  if ((tid & 63) == 0) part[tid >> 6] = vs;
  __syncthreads();
  float var = (part[0] + part[1] + part[2] + part[3]) * (1.f / 768.f);
  float inv = 1.0f / sqrtf(var + 1e-12f);
  #pragma unroll
  for (int i = 0; i < 3; ++i) {
    int f = tid + 256 * i;
    xnbf[(size_t)row * Hh + f] = f2bf((g[i] - mu) * inv * gam[f] + bet[f]);
  }
}

extern "C" void kernel_launch(void* const* d_in, const int* in_sizes, int n_in,
                              void* d_out, int out_size, void* d_ws, size_t ws_size,
                              hipStream_t stream)
{
  const float* hidden = (const float*)d_in[0];
  const int*   ptype  = (const int*)d_in[1];
  const float* W1     = (const float*)d_in[2];
  const float* b1     = (const float*)d_in[3];
  const float* vat    = (const float*)d_in[4];
  const float* Wfc    = (const float*)d_in[5];
  const float* bfc    = (const float*)d_in[6];
  const float* lng    = (const float*)d_in[7];
  const float* lnb    = (const float*)d_in[8];
  const float* Wout   = (const float*)d_in[9];
  const float* bout   = (const float*)d_in[10];

  float* out_hidd = (float*)d_out;
  float* out_logits = out_hidd + (size_t)Bb * Ss * Hh;

  // workspace layout (float offsets); xnbf reuses hbf (dead after FC GEMM)
  float* ws = (float*)d_ws;
  float* s_buf = ws;                                   // [0, 2048)
  float* e_buf = ws + 2048;                            // [2048, 4096)
  float* zpref = ws + 4096;                            // [4096, 6176)
  float* zsuf  = ws + 6176;                            // [6176, 8256)
  float* xbuf  = ws + 8256;                            // [8256, 1581120)
  float* spart = ws + 1581120;                         // [1581120, 1679424)
  unsigned short* hbf  = (unsigned short*)(ws + 1679424);   // 2048*768 bf16
  unsigned short* xnbf = hbf;                               // reuse (hbf dead)
  unsigned short* wfcb = (unsigned short*)(ws + 2465856);   // 768*768 bf16
  unsigned short* woutb = (unsigned short*)(ws + 2760768);  // 30522*768 bf16
  const size_t need = (size_t)2760768 * 4 + (size_t)Vv * Hh * 2;  // ~57.9 MB

  const bool pre = ws_size >= need;

  k1_score<<<dim3(Bb * Ss / K1_TOK), dim3(256), 0, stream>>>(hidden, W1, b1, vat, s_buf);
  k15_pre<<<dim3(Bb), dim3(256), 0, stream>>>(s_buf, e_buf, zpref, zsuf);
  if (pre) {
    wconv<<<dim3(256), dim3(256), 0, stream>>>(Wfc, wfcb, Hh * Hh / 4);
    wconv<<<dim3(2048), dim3(256), 0, stream>>>(Wout, woutb, Vv * Hh / 4);
  }
  k2a_part<<<dim3(Bb * 32 * 3), dim3(256), 0, stream>>>(hidden, e_buf, spart);
  k2c_scan<<<dim3(Bb * 16 * 3), dim3(256), 0, stream>>>(hidden, e_buf, zpref, zsuf,
                                                        spart, ptype, out_hidd, hbf);
  if (pre) {
    gemm4<<<dim3((2048 / 128) * (Hh / 128)), dim3(256), 0, stream>>>(
        hbf, wfcb, bfc, xbuf, 2048, Hh, Hh, 2048 / 128);
  } else {
    gemm_bt<<<dim3((2048 / GBM) * (Hh / GBN)), dim3(256), 0, stream>>>(
        hbf, Wfc, bfc, xbuf, 2048, Hh, Hh, 2048 / GBM);
  }
  k3b_geluln<<<dim3(2048), dim3(256), 0, stream>>>(xbuf, lng, lnb, xnbf);
  if (pre) {
    gemm4<<<dim3((2048 / 128) * ((Vv + 127) / 128)), dim3(256), 0, stream>>>(
        xnbf, woutb, bout, out_logits, 2048, Vv, Hh, 2048 / 128);
  } else {
    gemm_bt<<<dim3((2048 / GBM) * ((Vv + GBN - 1) / GBN)), dim3(256), 0, stream>>>(
        xnbf, Wout, bout, out_logits, 2048, Vv, Hh, 2048 / GBM);
  }
}